// Round 5
// baseline (163.287 us; speedup 1.0000x reference)
//
#include <hip/hip_runtime.h>

#define ND 12
#define NN 1024
#define NS 4095
#define NK 32
#define NC 10

// ws layout (floats): [0 .. 4095] cap_ws : unnormalized capacities (zeta output)

// One block, 512 threads: encoder -> latent -> hc -> increments -> zeta -> cap_ws + caps out
__global__ __launch_bounds__(512) void k_prep(
    const float* __restrict__ X,
    const float* __restrict__ w1, const float* __restrict__ b1,
    const float* __restrict__ w2, const float* __restrict__ b2,
    const float* __restrict__ lng, const float* __restrict__ lnb,
    const float* __restrict__ w3, const float* __restrict__ b3,
    const float* __restrict__ cw1, const float* __restrict__ cb1,
    const float* __restrict__ cw2, const float* __restrict__ cb2,
    float* __restrict__ cap_ws, float* __restrict__ out)
{
    __shared__ float arr[4096];     // 16 KB: zeta array
    __shared__ float part[8 * 16];  // per-wave latent partials
    __shared__ float lat_s[16];
    __shared__ float hc_s[16];

    int tid = threadIdx.x;
    int wv = tid >> 6, ln = tid & 63;

    // ---- encoder: 2 rows per thread (sequential, register-friendly) ----
    float acc[16];
    #pragma unroll
    for (int o = 0; o < 16; ++o) acc[o] = 0.f;

    #pragma unroll 1
    for (int rep = 0; rep < 2; ++rep) {
        int row = rep * 512 + tid;
        float x[ND];
        #pragma unroll
        for (int d = 0; d < ND; ++d) x[d] = X[row * ND + d];

        float h1[32];
        #pragma unroll
        for (int o = 0; o < 32; ++o) {
            float a = b1[o];
            #pragma unroll
            for (int d = 0; d < ND; ++d) a += w1[o * ND + d] * x[d];
            h1[o] = fmaxf(a, 0.f);
        }
        float h2[16];
        #pragma unroll
        for (int o = 0; o < 16; ++o) {
            float a = b2[o];
            #pragma unroll
            for (int k = 0; k < 32; ++k) a += w2[o * 32 + k] * h1[k];
            h2[o] = fmaxf(a, 0.f);
        }
        float mu = 0.f;
        #pragma unroll
        for (int o = 0; o < 16; ++o) mu += h2[o];
        mu *= (1.f / 16.f);
        float var = 0.f;
        #pragma unroll
        for (int o = 0; o < 16; ++o) { float t = h2[o] - mu; var += t * t; }
        var *= (1.f / 16.f);
        float inv = 1.f / sqrtf(var + 1e-5f);
        float hn[16];
        #pragma unroll
        for (int o = 0; o < 16; ++o) hn[o] = (h2[o] - mu) * inv * lng[o] + lnb[o];
        #pragma unroll
        for (int o = 0; o < 16; ++o) {
            float a = b3[o];
            #pragma unroll
            for (int k = 0; k < 16; ++k) a += w3[o * 16 + k] * hn[k];
            acc[o] += a;
        }
    }

    #pragma unroll
    for (int o = 0; o < 16; ++o) {
        float a = acc[o];
        #pragma unroll
        for (int s = 1; s < 64; s <<= 1) a += __shfl_xor(a, s, 64);
        if (ln == 0) part[wv * 16 + o] = a;
    }
    __syncthreads();

    if (tid < 16) {
        float a = 0.f;
        #pragma unroll
        for (int w = 0; w < 8; ++w) a += part[w * 16 + tid];
        lat_s[tid] = a * (1.f / 1024.f);
    }
    __syncthreads();
    if (tid < 16) {
        float a = cb1[tid];
        #pragma unroll
        for (int k = 0; k < 16; ++k) a += cw1[tid * 16 + k] * lat_s[k];
        hc_s[tid] = fmaxf(a, 0.f);
    }
    __syncthreads();

    // ---- increments: 8 subsets per thread, float4 weight loads ----
    float hc[16];
    #pragma unroll
    for (int k = 0; k < 16; ++k) hc[k] = hc_s[k];
    const float4* cw24 = reinterpret_cast<const float4*>(cw2);
    #pragma unroll 1
    for (int r = 0; r < 8; ++r) {
        int s = tid + r * 512;
        if (s < NS) {
            float4 wa = cw24[s * 4 + 0], wb = cw24[s * 4 + 1];
            float4 wc = cw24[s * 4 + 2], wd = cw24[s * 4 + 3];
            float a = cb2[s]
                + wa.x * hc[0]  + wa.y * hc[1]  + wa.z * hc[2]  + wa.w * hc[3]
                + wb.x * hc[4]  + wb.y * hc[5]  + wb.z * hc[6]  + wb.w * hc[7]
                + wc.x * hc[8]  + wc.y * hc[9]  + wc.z * hc[10] + wc.w * hc[11]
                + wd.x * hc[12] + wd.y * hc[13] + wd.z * hc[14] + wd.w * hc[15];
            arr[s + 1] = 0.1f / (1.f + __expf(-a));
        }
    }
    if (tid == 0) arr[0] = 0.f;
    __syncthreads();

    // ---- zeta transform (subset-sum over 12 dims) ----
    #pragma unroll 1
    for (int d = 0; d < ND; ++d) {
        int bit = 1 << d;
        #pragma unroll
        for (int r = 0; r < 4; ++r) {
            int i   = tid + r * 512;          // 0..2047
            int low = i & (bit - 1);
            int m   = ((i >> d) << (d + 1)) | bit | low;
            arr[m] += arr[m ^ bit];           // reads have bit clear: no intra-stage hazard
        }
        __syncthreads();
    }

    float inv = 1.f / (arr[4095] + 1e-8f);
    #pragma unroll
    for (int r = 0; r < 8; ++r) {
        int m = tid + r * 512;
        float c = arr[m];
        cap_ws[m] = c;
        if (m >= 1) out[NN * NC + m - 1] = c * inv;
    }
}

#define CSWAP(a,b) { float va=v[a], vb=v[b]; bool sw = va > vb; \
                     v[a]=sw?vb:va; v[b]=sw?va:vb; \
                     int ba=bm[a], bb=bm[b]; bm[a]=sw?bb:ba; bm[b]=sw?ba:bb; }

// Fused: per-row sims (4/thread, registers) + exact top-32 via 42-bit radix
// select (softmax-vote is permutation-invariant so only the SET is needed;
// tie-break = jax lower-index via key = mapped<<10 | (1023-j))
__global__ __launch_bounds__(256) void k_simsel(
    const float* __restrict__ X, const int* __restrict__ y,
    const float* __restrict__ cap_ws, float* __restrict__ out)
{
    __shared__ float    cap[4096];     // 16 KB
    __shared__ unsigned bins[2048];    // 8 KB
    __shared__ unsigned wt_u[4];
    __shared__ unsigned ctl_bin, ctl_need;
    __shared__ unsigned vmax_u[4];
    __shared__ float    wsum_s[4];
    __shared__ float    fbins[NC];

    int tid = threadIdx.x, i = blockIdx.x;
    int wv = tid >> 6, ln = tid & 63;

    const float4* cap4 = reinterpret_cast<const float4*>(cap_ws);
    #pragma unroll
    for (int t = 0; t < 4; ++t)
        reinterpret_cast<float4*>(cap)[tid + 256 * t] = cap4[tid + 256 * t];

    const float4* X4 = reinterpret_cast<const float4*>(X);
    float xi[ND];
    {
        float4 a = X4[i * 3], b = X4[i * 3 + 1], c = X4[i * 3 + 2];
        xi[0]=a.x; xi[1]=a.y; xi[2]=a.z; xi[3]=a.w;
        xi[4]=b.x; xi[5]=b.y; xi[6]=b.z; xi[7]=b.w;
        xi[8]=c.x; xi[9]=c.y; xi[10]=c.z; xi[11]=c.w;
    }
    float inv = 1.f / (cap_ws[4095] + 1e-8f);
    __syncthreads();

    // ---- sims: 4 pairs per thread, keys in registers ----
    unsigned long long kreg[4];
    #pragma unroll
    for (int t = 0; t < 4; ++t) {
        int j = t * 256 + tid;
        float xr[ND];
        {
            float4 a = X4[j * 3], b = X4[j * 3 + 1], c = X4[j * 3 + 2];
            xr[0]=a.x; xr[1]=a.y; xr[2]=a.z; xr[3]=a.w;
            xr[4]=b.x; xr[5]=b.y; xr[6]=b.z; xr[7]=b.w;
            xr[8]=c.x; xr[9]=c.y; xr[10]=c.z; xr[11]=c.w;
        }
        float v[ND]; int bm[ND];
        #pragma unroll
        for (int d = 0; d < ND; ++d) {
            v[d]  = __expf(-fabsf(xi[d] - xr[d]));
            bm[d] = 1 << d;
        }
        // Batcher odd-even mergesort, 12 inputs, 41 CEs
        CSWAP(0,1)  CSWAP(0,2)  CSWAP(1,2)  CSWAP(3,4)  CSWAP(3,5)  CSWAP(4,5)
        CSWAP(0,3)  CSWAP(2,5)  CSWAP(2,3)  CSWAP(1,4)  CSWAP(1,2)  CSWAP(3,4)
        CSWAP(6,7)  CSWAP(6,8)  CSWAP(7,8)  CSWAP(9,10) CSWAP(9,11) CSWAP(10,11)
        CSWAP(6,9)  CSWAP(8,11) CSWAP(8,9)  CSWAP(7,10) CSWAP(7,8)  CSWAP(9,10)
        CSWAP(0,6)  CSWAP(4,10) CSWAP(4,6)  CSWAP(2,8)  CSWAP(2,4)  CSWAP(6,8)
        CSWAP(1,7)  CSWAP(5,11) CSWAP(5,7)  CSWAP(3,9)  CSWAP(3,5)  CSWAP(7,9)
        CSWAP(1,2)  CSWAP(3,4)  CSWAP(5,6)  CSWAP(7,8)  CSWAP(9,10)

        int tail = 0; float sim = 0.f;
        #pragma unroll
        for (int k = ND - 1; k >= 0; --k) {
            tail |= bm[k];
            float pv = (k > 0) ? v[k - 1] : 0.f;
            sim += (v[k] - pv) * cap[tail];
        }
        sim *= inv;

        unsigned u = __float_as_uint(sim);
        u = (u & 0x80000000u) ? ~u : (u | 0x80000000u);
        if (j == i) u = 0u;
        kreg[t] = (((unsigned long long)u) << 10) | (unsigned)(1023 - j);
    }

    // ---- block max of mapped values (softmax stabilizer = top-1 sim) ----
    unsigned mv = 0;
    #pragma unroll
    for (int t = 0; t < 4; ++t) {
        unsigned x = (unsigned)(kreg[t] >> 10);
        mv = (x > mv) ? x : mv;
    }
    #pragma unroll
    for (int s = 1; s < 64; s <<= 1) {
        unsigned o = __shfl_xor(mv, s, 64);
        mv = (o > mv) ? o : mv;
    }
    if (ln == 0) vmax_u[wv] = mv;

    // ---- radix select: find 32nd-largest 42-bit key ----
    unsigned long long prefix = 0;
    unsigned need = NK;
    #pragma unroll 1
    for (int lev = 0; lev < 4; ++lev) {
        int shift   = (lev < 3) ? (31 - 11 * lev) : 0;
        int bits    = (lev < 3) ? 11 : 9;
        int topbits = shift + bits;
        unsigned mask = (1u << bits) - 1u;

        uint4 z; z.x = z.y = z.z = z.w = 0u;
        reinterpret_cast<uint4*>(bins)[tid * 2]     = z;
        reinterpret_cast<uint4*>(bins)[tid * 2 + 1] = z;
        __syncthreads();

        #pragma unroll
        for (int t = 0; t < 4; ++t) {
            unsigned long long k = kreg[t];
            if ((k >> topbits) == prefix)
                atomicAdd(&bins[(unsigned)(k >> shift) & mask], 1u);
        }
        __syncthreads();

        unsigned s8[8]; unsigned S = 0;
        int base = tid * 8;
        #pragma unroll
        for (int r = 0; r < 8; ++r) { s8[r] = bins[base + r]; S += s8[r]; }
        unsigned v = S;
        #pragma unroll
        for (int off = 1; off < 64; off <<= 1) {
            unsigned o = __shfl_down(v, off, 64);
            if (ln + off < 64) v += o;
        }
        if (ln == 0) wt_u[wv] = v;   // wave total
        __syncthreads();
        unsigned G = v - S;          // strictly-above within wave
        #pragma unroll
        for (int w2 = 0; w2 < 4; ++w2) if (w2 > wv) G += wt_u[w2];

        unsigned cum = G;
        #pragma unroll
        for (int r = 7; r >= 0; --r) {
            unsigned c = s8[r];
            if (cum < need && cum + c >= need) { ctl_bin = (unsigned)(base + r); ctl_need = need - cum; }
            cum += c;
        }
        __syncthreads();
        prefix = (prefix << bits) | ctl_bin;
        need   = ctl_need;
        __syncthreads();
    }
    unsigned long long T = prefix;   // exact 32nd-largest key

    // ---- softmax weights over the selected set + vote ----
    unsigned m0 = vmax_u[0], m1 = vmax_u[1], m2 = vmax_u[2], m3 = vmax_u[3];
    mv = (m1 > m0) ? m1 : m0;
    mv = (m2 > mv) ? m2 : mv;
    mv = (m3 > mv) ? m3 : mv;
    float vmax = (mv & 0x80000000u) ? __uint_as_float(mv & 0x7fffffffu) : __uint_as_float(~mv);

    float wr[4]; float wpart = 0.f;
    #pragma unroll
    for (int t = 0; t < 4; ++t) {
        bool sel = kreg[t] >= T;
        unsigned su = (unsigned)(kreg[t] >> 10);
        float val = (su & 0x80000000u) ? __uint_as_float(su & 0x7fffffffu) : __uint_as_float(~su);
        float w = __expf((val - vmax) * 2.0f);   // /TEMP, TEMP=0.5
        w = sel ? w : 0.f;
        wr[t] = w; wpart += w;
    }
    #pragma unroll
    for (int s = 1; s < 64; s <<= 1) wpart += __shfl_xor(wpart, s, 64);
    if (ln == 0) wsum_s[wv] = wpart;
    if (tid < NC) fbins[tid] = 0.f;
    __syncthreads();
    float wsum = wsum_s[0] + wsum_s[1] + wsum_s[2] + wsum_s[3];
    #pragma unroll
    for (int t = 0; t < 4; ++t)
        if (wr[t] != 0.f) atomicAdd(&fbins[y[t * 256 + tid]], wr[t]);
    __syncthreads();
    if (tid < NC) out[i * NC + tid] = fbins[tid] / wsum;
}

extern "C" void kernel_launch(void* const* d_in, const int* in_sizes, int n_in,
                              void* d_out, int out_size, void* d_ws, size_t ws_size,
                              hipStream_t stream)
{
    const float* X   = (const float*)d_in[0];
    const int*   y   = (const int*)  d_in[1];
    const float* w1  = (const float*)d_in[2];
    const float* b1  = (const float*)d_in[3];
    const float* w2  = (const float*)d_in[4];
    const float* b2  = (const float*)d_in[5];
    const float* lng = (const float*)d_in[6];
    const float* lnb = (const float*)d_in[7];
    const float* w3  = (const float*)d_in[8];
    const float* b3  = (const float*)d_in[9];
    const float* cw1 = (const float*)d_in[10];
    const float* cb1 = (const float*)d_in[11];
    const float* cw2 = (const float*)d_in[12];
    const float* cb2 = (const float*)d_in[13];
    float* out = (float*)d_out;
    float* ws  = (float*)d_ws;

    float* cap_ws = ws;   // 4096 floats

    k_prep  <<<1,  512, 0, stream>>>(X, w1, b1, w2, b2, lng, lnb, w3, b3,
                                     cw1, cb1, cw2, cb2, cap_ws, out);
    k_simsel<<<NN, 256, 0, stream>>>(X, y, cap_ws, out);
}

// Round 6
// 119.620 us; speedup vs baseline: 1.3650x; 1.3650x over previous
//
#include <hip/hip_runtime.h>

#define ND 12
#define NN 1024
#define NS 4095
#define NK 32
#define NC 10
#define LOG2E 1.4426950408889634f

// ws layout (floats):
//  [0     .. 4095 ]  cap_ws : unnormalized capacities (zeta output), bitmask-indexed
//  [4096  .. 4351 ]  part   : 16 x 16 latent partial sums (8 blocks x 2 waves)
//  [8192  .. 12287]  inc    : increments, bitmask-indexed (inc[0] = 0)
//  [16384 .. 28671]  X2     : X * log2(e), row-major [1024][12]

// 8 blocks x 128 threads, 1 row/thread. Weights staged in LDS (the R5 lesson:
// per-thread uniform global loads stall ~100-900cy each with few waves).
__global__ __launch_bounds__(128) void k_enc(
    const float* __restrict__ X,
    const float* __restrict__ w1, const float* __restrict__ b1,
    const float* __restrict__ w2, const float* __restrict__ b2,
    const float* __restrict__ lng, const float* __restrict__ lnb,
    const float* __restrict__ w3, const float* __restrict__ b3,
    float* __restrict__ part, float* __restrict__ x2)
{
    __shared__ float sw[1248];
    // offsets: w1 0..383 | b1 384..415 | w2 416..927 | b2 928..943
    //          lng 944..959 | lnb 960..975 | w3 976..1231 | b3 1232..1247
    int tid = threadIdx.x;
    int row = blockIdx.x * 128 + tid;
    int wv = tid >> 6, ln = tid & 63;

    for (int k = tid; k < 384; k += 128) sw[k] = w1[k];
    if (tid < 32) sw[384 + tid] = b1[tid];
    for (int k = tid; k < 512; k += 128) sw[416 + k] = w2[k];
    if (tid < 16) {
        sw[928 + tid]  = b2[tid];
        sw[944 + tid]  = lng[tid];
        sw[960 + tid]  = lnb[tid];
        sw[1232 + tid] = b3[tid];
    }
    for (int k = tid; k < 256; k += 128) sw[976 + k] = w3[k];

    const float4* X4 = reinterpret_cast<const float4*>(X);
    float x[ND];
    {
        float4 a = X4[row * 3], b = X4[row * 3 + 1], c = X4[row * 3 + 2];
        x[0]=a.x; x[1]=a.y; x[2]=a.z; x[3]=a.w;
        x[4]=b.x; x[5]=b.y; x[6]=b.z; x[7]=b.w;
        x[8]=c.x; x[9]=c.y; x[10]=c.z; x[11]=c.w;
    }
    // pre-scaled copy for simsel's exp2 path
    {
        float4 a, b, c;
        a.x=x[0]*LOG2E; a.y=x[1]*LOG2E; a.z=x[2]*LOG2E;  a.w=x[3]*LOG2E;
        b.x=x[4]*LOG2E; b.y=x[5]*LOG2E; b.z=x[6]*LOG2E;  b.w=x[7]*LOG2E;
        c.x=x[8]*LOG2E; c.y=x[9]*LOG2E; c.z=x[10]*LOG2E; c.w=x[11]*LOG2E;
        float4* x24 = reinterpret_cast<float4*>(x2);
        x24[row * 3] = a; x24[row * 3 + 1] = b; x24[row * 3 + 2] = c;
    }
    __syncthreads();

    float h1[32];
    #pragma unroll
    for (int o = 0; o < 32; ++o) {
        float a = sw[384 + o];
        #pragma unroll
        for (int d = 0; d < ND; ++d) a += sw[o * ND + d] * x[d];
        h1[o] = fmaxf(a, 0.f);
    }
    float h2[16];
    #pragma unroll
    for (int o = 0; o < 16; ++o) {
        float a = sw[928 + o];
        #pragma unroll
        for (int k = 0; k < 32; ++k) a += sw[416 + o * 32 + k] * h1[k];
        h2[o] = fmaxf(a, 0.f);
    }
    float mu = 0.f;
    #pragma unroll
    for (int o = 0; o < 16; ++o) mu += h2[o];
    mu *= (1.f / 16.f);
    float var = 0.f;
    #pragma unroll
    for (int o = 0; o < 16; ++o) { float t = h2[o] - mu; var += t * t; }
    var *= (1.f / 16.f);
    float inv = 1.f / sqrtf(var + 1e-5f);
    float hn[16];
    #pragma unroll
    for (int o = 0; o < 16; ++o) hn[o] = (h2[o] - mu) * inv * sw[944 + o] + sw[960 + o];

    #pragma unroll
    for (int o = 0; o < 16; ++o) {
        float a = sw[1232 + o];
        #pragma unroll
        for (int k = 0; k < 16; ++k) a += sw[976 + o * 16 + k] * hn[k];
        #pragma unroll
        for (int s = 1; s < 64; s <<= 1) a += __shfl_xor(a, s, 64);
        if (ln == 0) part[(blockIdx.x * 2 + wv) * 16 + o] = a;
    }
}

__global__ __launch_bounds__(256) void k_inc(
    const float* __restrict__ part,
    const float* __restrict__ cw1, const float* __restrict__ cb1,
    const float* __restrict__ cw2, const float* __restrict__ cb2,
    float* __restrict__ inc)
{
    __shared__ float lat_s[16];
    __shared__ float hc_s[16];
    int tid = threadIdx.x;

    if (tid < 16) {
        float a = 0.f;
        #pragma unroll
        for (int b = 0; b < 16; ++b) a += part[b * 16 + tid];
        lat_s[tid] = a * (1.f / 1024.f);
    }
    __syncthreads();
    if (tid < 16) {
        float a = cb1[tid];
        #pragma unroll
        for (int k = 0; k < 16; ++k) a += cw1[tid * 16 + k] * lat_s[k];
        hc_s[tid] = fmaxf(a, 0.f);
    }
    __syncthreads();

    int e = blockIdx.x * 1024 + tid * 4;
    int s = e >> 4;
    if (s < NS) {
        float4 w = *reinterpret_cast<const float4*>(cw2 + e);
        int k0 = e & 15;
        float p = w.x * hc_s[k0] + w.y * hc_s[k0 + 1] + w.z * hc_s[k0 + 2] + w.w * hc_s[k0 + 3];
        p += __shfl_xor(p, 1, 64);
        p += __shfl_xor(p, 2, 64);
        if ((tid & 3) == 0) {
            float a = p + cb2[s];
            inc[s + 1] = 0.1f / (1.f + __expf(-a));
        }
    }
    if (blockIdx.x == 0 && tid == 0) inc[0] = 0.f;
}

__global__ __launch_bounds__(1024) void k_zeta(
    const float* __restrict__ inc, float* __restrict__ cap_ws, float* __restrict__ out)
{
    __shared__ float arr[4096];
    int tid = threadIdx.x;

    *reinterpret_cast<float4*>(arr + tid * 4) = *reinterpret_cast<const float4*>(inc + tid * 4);
    __syncthreads();

    #pragma unroll 1
    for (int d = 0; d < ND; ++d) {
        int bit = 1 << d;
        #pragma unroll
        for (int r = 0; r < 2; ++r) {
            int i   = tid + r * 1024;
            int low = i & (bit - 1);
            int m   = ((i >> d) << (d + 1)) | bit | low;
            arr[m] += arr[m ^ bit];    // reads have bit clear: no intra-stage hazard
        }
        __syncthreads();
    }

    float inv = 1.f / (arr[4095] + 1e-8f);
    #pragma unroll
    for (int r = 0; r < 4; ++r) {
        int m = tid * 4 + r;
        cap_ws[m] = arr[m];
        if (m >= 1) out[NN * NC + m - 1] = arr[m] * inv;
    }
}

#define CSWAP(a,b) { float va=v[a], vb=v[b]; bool sw = va > vb; \
                     v[a]=sw?vb:va; v[b]=sw?va:vb; \
                     int ba=bm[a], bb=bm[b]; bm[a]=sw?bb:ba; bm[b]=sw?ba:bb; }

// Fused: per-row sims (4/thread, registers) + exact top-32 via 42-bit radix
// select (softmax-vote is permutation-invariant so only the SET is needed;
// tie-break = jax lower-index via key = mapped<<10 | (1023-j))
__global__ __launch_bounds__(256) void k_simsel(
    const float* __restrict__ x2, const int* __restrict__ y,
    const float* __restrict__ cap_ws, float* __restrict__ out)
{
    __shared__ float    cap[4096];     // 16 KB
    __shared__ unsigned bins[2048];    // 8 KB
    __shared__ unsigned wt_u[4];
    __shared__ unsigned ctl_bin, ctl_need;
    __shared__ unsigned vmax_u[4];
    __shared__ float    wsum_s[4];
    __shared__ float    fbins[NC];

    int tid = threadIdx.x, i = blockIdx.x;
    int wv = tid >> 6, ln = tid & 63;

    const float4* cap4 = reinterpret_cast<const float4*>(cap_ws);
    #pragma unroll
    for (int t = 0; t < 4; ++t)
        reinterpret_cast<float4*>(cap)[tid + 256 * t] = cap4[tid + 256 * t];

    // initial bin clear + fbins clear, covered by the cap-staging barrier
    {
        uint4 z; z.x = z.y = z.z = z.w = 0u;
        reinterpret_cast<uint4*>(bins)[tid * 2]     = z;
        reinterpret_cast<uint4*>(bins)[tid * 2 + 1] = z;
    }
    if (tid < NC) fbins[tid] = 0.f;

    const float4* X4 = reinterpret_cast<const float4*>(x2);
    float xi[ND];
    {
        float4 a = X4[i * 3], b = X4[i * 3 + 1], c = X4[i * 3 + 2];
        xi[0]=a.x; xi[1]=a.y; xi[2]=a.z; xi[3]=a.w;
        xi[4]=b.x; xi[5]=b.y; xi[6]=b.z; xi[7]=b.w;
        xi[8]=c.x; xi[9]=c.y; xi[10]=c.z; xi[11]=c.w;
    }
    float inv = 1.f / (cap_ws[4095] + 1e-8f);
    __syncthreads();

    // ---- sims: 4 pairs per thread, keys in registers ----
    unsigned long long kreg[4];
    #pragma unroll
    for (int t = 0; t < 4; ++t) {
        int j = t * 256 + tid;
        float xr[ND];
        {
            float4 a = X4[j * 3], b = X4[j * 3 + 1], c = X4[j * 3 + 2];
            xr[0]=a.x; xr[1]=a.y; xr[2]=a.z; xr[3]=a.w;
            xr[4]=b.x; xr[5]=b.y; xr[6]=b.z; xr[7]=b.w;
            xr[8]=c.x; xr[9]=c.y; xr[10]=c.z; xr[11]=c.w;
        }
        float v[ND]; int bm[ND];
        #pragma unroll
        for (int d = 0; d < ND; ++d) {
            v[d]  = exp2f(-fabsf(xi[d] - xr[d]));   // X pre-scaled by log2e
            bm[d] = 1 << d;
        }
        // Batcher odd-even mergesort, 12 inputs, 41 CEs
        CSWAP(0,1)  CSWAP(0,2)  CSWAP(1,2)  CSWAP(3,4)  CSWAP(3,5)  CSWAP(4,5)
        CSWAP(0,3)  CSWAP(2,5)  CSWAP(2,3)  CSWAP(1,4)  CSWAP(1,2)  CSWAP(3,4)
        CSWAP(6,7)  CSWAP(6,8)  CSWAP(7,8)  CSWAP(9,10) CSWAP(9,11) CSWAP(10,11)
        CSWAP(6,9)  CSWAP(8,11) CSWAP(8,9)  CSWAP(7,10) CSWAP(7,8)  CSWAP(9,10)
        CSWAP(0,6)  CSWAP(4,10) CSWAP(4,6)  CSWAP(2,8)  CSWAP(2,4)  CSWAP(6,8)
        CSWAP(1,7)  CSWAP(5,11) CSWAP(5,7)  CSWAP(3,9)  CSWAP(3,5)  CSWAP(7,9)
        CSWAP(1,2)  CSWAP(3,4)  CSWAP(5,6)  CSWAP(7,8)  CSWAP(9,10)

        int tail = 0; float sim = 0.f;
        #pragma unroll
        for (int k = ND - 1; k >= 0; --k) {
            tail |= bm[k];
            float pv = (k > 0) ? v[k - 1] : 0.f;
            sim += (v[k] - pv) * cap[tail];
        }
        sim *= inv;

        unsigned u = __float_as_uint(sim);
        u = (u & 0x80000000u) ? ~u : (u | 0x80000000u);
        if (j == i) u = 0u;
        kreg[t] = (((unsigned long long)u) << 10) | (unsigned)(1023 - j);
    }

    // ---- block max of mapped values (softmax stabilizer = top-1 sim) ----
    unsigned mv = 0;
    #pragma unroll
    for (int t = 0; t < 4; ++t) {
        unsigned x = (unsigned)(kreg[t] >> 10);
        mv = (x > mv) ? x : mv;
    }
    #pragma unroll
    for (int s = 1; s < 64; s <<= 1) {
        unsigned o = __shfl_xor(mv, s, 64);
        mv = (o > mv) ? o : mv;
    }
    if (ln == 0) vmax_u[wv] = mv;

    // ---- radix select: find 32nd-largest 42-bit key (3 barriers/level) ----
    unsigned long long prefix = 0;
    unsigned need = NK;
    #pragma unroll 1
    for (int lev = 0; lev < 4; ++lev) {
        int shift   = (lev < 3) ? (31 - 11 * lev) : 0;
        int bits    = (lev < 3) ? 11 : 9;
        int topbits = shift + bits;
        unsigned mask = (1u << bits) - 1u;

        // bins are zero here (initial clear, or owner-clear last level)
        #pragma unroll
        for (int t = 0; t < 4; ++t) {
            unsigned long long k = kreg[t];
            if ((k >> topbits) == prefix)
                atomicAdd(&bins[(unsigned)(k >> shift) & mask], 1u);
        }
        __syncthreads();                                   // B1: counts stable

        unsigned s8[8]; unsigned S = 0;
        int base = tid * 8;
        #pragma unroll
        for (int r = 0; r < 8; ++r) { s8[r] = bins[base + r]; S += s8[r]; }
        {   // owner-exclusive clear for the next level
            uint4 z; z.x = z.y = z.z = z.w = 0u;
            reinterpret_cast<uint4*>(bins)[tid * 2]     = z;
            reinterpret_cast<uint4*>(bins)[tid * 2 + 1] = z;
        }
        unsigned v = S;
        #pragma unroll
        for (int off = 1; off < 64; off <<= 1) {
            unsigned o = __shfl_down(v, off, 64);
            if (ln + off < 64) v += o;
        }
        if (ln == 0) wt_u[wv] = v;
        __syncthreads();                                   // B2: wt_u visible
        unsigned G = v - S;          // strictly-above within wave
        #pragma unroll
        for (int w2 = 0; w2 < 4; ++w2) if (w2 > wv) G += wt_u[w2];

        unsigned cum = G;
        #pragma unroll
        for (int r = 7; r >= 0; --r) {
            unsigned c = s8[r];
            if (cum < need && cum + c >= need) { ctl_bin = (unsigned)(base + r); ctl_need = need - cum; }
            cum += c;
        }
        __syncthreads();                                   // B3: ctl visible
        prefix = (prefix << bits) | ctl_bin;
        need   = ctl_need;
    }
    unsigned long long T = prefix;   // exact 32nd-largest key

    // ---- softmax weights over the selected set + vote ----
    unsigned m0 = vmax_u[0], m1 = vmax_u[1], m2 = vmax_u[2], m3 = vmax_u[3];
    mv = (m1 > m0) ? m1 : m0;
    mv = (m2 > mv) ? m2 : mv;
    mv = (m3 > mv) ? m3 : mv;
    float vmax = (mv & 0x80000000u) ? __uint_as_float(mv & 0x7fffffffu) : __uint_as_float(~mv);

    float wr[4]; float wpart = 0.f;
    #pragma unroll
    for (int t = 0; t < 4; ++t) {
        bool sel = kreg[t] >= T;
        unsigned su = (unsigned)(kreg[t] >> 10);
        float val = (su & 0x80000000u) ? __uint_as_float(su & 0x7fffffffu) : __uint_as_float(~su);
        float w = __expf((val - vmax) * 2.0f);   // /TEMP, TEMP=0.5
        w = sel ? w : 0.f;
        wr[t] = w; wpart += w;
    }
    #pragma unroll
    for (int s = 1; s < 64; s <<= 1) wpart += __shfl_xor(wpart, s, 64);
    if (ln == 0) wsum_s[wv] = wpart;
    __syncthreads();
    float wsum = wsum_s[0] + wsum_s[1] + wsum_s[2] + wsum_s[3];
    #pragma unroll
    for (int t = 0; t < 4; ++t)
        if (wr[t] != 0.f) atomicAdd(&fbins[y[t * 256 + tid]], wr[t]);
    __syncthreads();
    if (tid < NC) out[i * NC + tid] = fbins[tid] / wsum;
}

extern "C" void kernel_launch(void* const* d_in, const int* in_sizes, int n_in,
                              void* d_out, int out_size, void* d_ws, size_t ws_size,
                              hipStream_t stream)
{
    const float* X   = (const float*)d_in[0];
    const int*   y   = (const int*)  d_in[1];
    const float* w1  = (const float*)d_in[2];
    const float* b1  = (const float*)d_in[3];
    const float* w2  = (const float*)d_in[4];
    const float* b2  = (const float*)d_in[5];
    const float* lng = (const float*)d_in[6];
    const float* lnb = (const float*)d_in[7];
    const float* w3  = (const float*)d_in[8];
    const float* b3  = (const float*)d_in[9];
    const float* cw1 = (const float*)d_in[10];
    const float* cb1 = (const float*)d_in[11];
    const float* cw2 = (const float*)d_in[12];
    const float* cb2 = (const float*)d_in[13];
    float* out = (float*)d_out;
    float* ws  = (float*)d_ws;

    float* cap_ws = ws;           // 4096 floats
    float* part   = ws + 4096;    // 256 floats
    float* inc    = ws + 8192;    // 4096 floats
    float* x2     = ws + 16384;   // 12288 floats

    k_enc   <<<8,  128,  0, stream>>>(X, w1, b1, w2, b2, lng, lnb, w3, b3, part, x2);
    k_inc   <<<64, 256,  0, stream>>>(part, cw1, cb1, cw2, cb2, inc);
    k_zeta  <<<1,  1024, 0, stream>>>(inc, cap_ws, out);
    k_simsel<<<NN, 256,  0, stream>>>(x2, y, cap_ws, out);
}